// Round 9
// baseline (596.888 us; speedup 1.0000x reference)
//
#include <hip/hip_runtime.h>
#include <stdint.h>

#define NN    50000
#define INC   128
#define HIDC  256
#define OUTC  40
#define GCH   128
#define NL    4
#define NG    2
#define NEDGE 600000
#define EPSV  1e-5f

typedef __bf16 bf16x8 __attribute__((ext_vector_type(8)));
typedef float  f32x4  __attribute__((ext_vector_type(4)));
typedef unsigned short u16x4 __attribute__((ext_vector_type(4)));
typedef unsigned short u16x8 __attribute__((ext_vector_type(8)));

__device__ __forceinline__ float bf2f(unsigned short u) {
    union { float f; unsigned int i; } v;
    v.i = ((unsigned int)u) << 16;
    return v.f;
}
__device__ __forceinline__ unsigned short f2bf(float f) {
    union { float f; unsigned int i; } v;
    v.f = f;
    unsigned int u = v.i;
    u += 0x7FFFu + ((u >> 16) & 1u);   // RNE
    return (unsigned short)(u >> 16);
}
__device__ __forceinline__ float ldf(const void* p, int is_f32, long long i) {
    if (is_f32) return ((const float*)p)[i];
    return bf2f(((const unsigned short*)p)[i]);
}
__device__ __forceinline__ bf16x8 ld8(const unsigned short* p) {
    return *(const bf16x8*)p;
}
// async global->LDS, 16B/lane. Dest is wave-base + lane*16 (linear pattern).
__device__ __forceinline__ void gload_lds16(const void* g, void* l) {
    __builtin_amdgcn_global_load_lds(
        (const __attribute__((address_space(1))) unsigned int*)g,
        (__attribute__((address_space(3))) unsigned int*)l,
        16, 0, 0);
}

// ---- diagnostic marker ----
__global__ void k_marker(void* out, float val, int n) {
    int i = blockIdx.x * 256 + threadIdx.x;
    if (i < n) ((unsigned short*)out)[i] = f2bf(val);
}

// ---- fused prep: zero deg + detect dtypes + convert weights/params ----
#define CVT_W1  32768
#define CVT_CW  131072
#define CVT_W2  12288
#define CVT_TOT (CVT_W1 + CVT_CW + CVT_W2)   // 176128 = 688*256

__global__ void k_prep(const void* x, const int* ei,
                       const void* w1, const void* cw, const void* w2,
                       const void* b1, const void* ng, const void* nb, const void* cb,
                       const void* fg, const void* fb, const void* b2,
                       int* flags, int* deg,
                       unsigned short* w1t, unsigned short* cwt, unsigned short* w2t,
                       float* b1f, float* ngf, float* nbf, float* cbf,
                       float* fgf, float* fbf, float* b2f) {
    int t = threadIdx.x, b = blockIdx.x;
    if (b < 196) {
        int gid = b * 256 + t;
        if (gid < NN) deg[gid] = 0;
        if (b == 0) {
            __shared__ int hi_or, wild_cnt;
            if (t == 0) { hi_or = 0; wild_cnt = 0; }
            __syncthreads();
            int acc = 0;
            for (int i = 0; i < 8; i++) acc |= ei[2 * (t + i * 256) + 1];
            if (acc) atomicOr(&hi_or, 1);
            int wild = 0;
            for (int i = 0; i < 2; i++) {
                unsigned short u = ((const unsigned short*)x)[t + i * 256];
                int e = (u >> 7) & 0xFF;
                if (e <= 0x30 || e >= 0xC0) wild++;
            }
            atomicAdd(&wild_cnt, wild);
            __syncthreads();
            if (t == 0) {
                flags[0] = hi_or ? 0 : 1;           // 1 => int64 edge_index
                flags[1] = (wild_cnt > 32) ? 1 : 0; // 1 => fp32 float tensors
            }
        }
        return;
    }
    // conversion blocks: derive f32-ness locally (same probe, same threshold)
    __shared__ int wc;
    if (t == 0) wc = 0;
    __syncthreads();
    int wild = 0;
    for (int i = 0; i < 2; i++) {
        unsigned short u = ((const unsigned short*)x)[t + i * 256];
        int e = (u >> 7) & 0xFF;
        if (e <= 0x30 || e >= 0xC0) wild++;
    }
    atomicAdd(&wc, wild);
    __syncthreads();
    int f32 = (wc > 32) ? 1 : 0;
    int cb2 = b - 196;
    if (cb2 == 688) {   // params
        b1f[t] = ldf(b1, f32, t);
        fgf[t] = ldf(fg, f32, t);
        fbf[t] = ldf(fb, f32, t);
        if (t < 48) b2f[t] = (t < OUTC) ? ldf(b2, f32, t) : 0.0f;
        for (int i = 0; i < 4; i++) {
            int j = t + i * 256;
            ngf[j] = ldf(ng, f32, j);
            nbf[j] = ldf(nb, f32, j);
            cbf[j] = ldf(cb, f32, j);
        }
        return;
    }
    long long j = (long long)cb2 * 256 + t;
    if (j >= CVT_TOT) return;
    if (j < CVT_W1) {
        int n = (int)(j >> 7), k = (int)(j & 127);
        w1t[n * 128 + (k ^ ((n & 7) << 3))] = f2bf(ldf(w1, f32, (long long)k * HIDC + n));
    } else if (j < CVT_W1 + CVT_CW) {
        long long jj = j - CVT_W1;
        int lg = (int)(jj >> 14);
        int rem = (int)(jj & 16383);
        int n = rem >> 7, k = rem & 127;
        cwt[lg * 16384 + n * 128 + (k ^ ((n & 7) << 3))] =
            f2bf(ldf(cw, f32, (long long)lg * GCH * GCH + (long long)k * GCH + n));
    } else {
        long long jj = j - (CVT_W1 + CVT_CW);
        int n = (int)(jj >> 8), k = (int)(jj & 255);
        w2t[n * 256 + (k ^ ((n & 7) << 3))] =
            (n < OUTC) ? f2bf(ldf(w2, f32, (long long)k * OUTC + n)) : (unsigned short)0;
    }
}

// ---- CSR count ----
__global__ void k_count(const int* __restrict__ ei, const int* __restrict__ flags,
                        int* __restrict__ deg) {
    int e = (blockIdx.x * 256 + threadIdx.x) * 2;
    if (e >= NEDGE) return;
    int d0, d1;
    if (flags[0]) {
        int4 v = *(const int4*)(ei + 2 * (NEDGE + e));
        d0 = v.x; d1 = v.z;
    } else {
        int2 v = *(const int2*)(ei + NEDGE + e);
        d0 = v.x; d1 = v.y;
    }
    atomicAdd(&deg[d0], 1);
    if (e + 1 < NEDGE) atomicAdd(&deg[d1], 1);
}

// ---- fused scan ----
#define SCAN_B 49
__global__ void k_scan(const int* __restrict__ deg,
                       int* __restrict__ rowptr, int* __restrict__ cursor) {
    __shared__ int part[256];
    __shared__ int bbase_s;
    int b = blockIdx.x, t = threadIdx.x;
    int lim = b * 1024;
    int pre = 0;
    for (int i = t; i < lim; i += 256) pre += deg[i];
    part[t] = pre;
    __syncthreads();
    for (int off = 128; off > 0; off >>= 1) {
        if (t < off) part[t] += part[t + off];
        __syncthreads();
    }
    if (t == 0) bbase_s = part[0];
    __syncthreads();

    int base = b * 1024 + t * 4;
    int v[4];
    int s = 0;
#pragma unroll
    for (int j = 0; j < 4; j++) {
        int i = base + j;
        v[j] = (i < NN) ? deg[i] : 0;
        s += v[j];
    }
    part[t] = s;
    __syncthreads();
    for (int off = 1; off < 256; off <<= 1) {
        int x = (t >= off) ? part[t - off] : 0;
        __syncthreads();
        part[t] += x;
        __syncthreads();
    }
    int run = bbase_s + part[t] - s;
#pragma unroll
    for (int j = 0; j < 4; j++) {
        int i = base + j;
        if (i < NN) { rowptr[i] = run; cursor[i] = run; }
        run += v[j];
    }
    if (b == SCAN_B - 1 && t == 255) rowptr[NN] = NEDGE;
}

// packed fill: ONE 4B store per edge — (bf16 weight << 16) | src (src < 65536)
__global__ void k_fill(const int* __restrict__ ei, const void* __restrict__ ew,
                       const int* __restrict__ flags,
                       int* __restrict__ cursor, unsigned int* __restrict__ epk) {
    int e = (blockIdx.x * 256 + threadIdx.x) * 2;
    if (e >= NEDGE) return;
    int is64 = flags[0];
    int f32 = flags[1];
    int d0, s0, d1 = 0, s1 = 0;
    int has1 = (e + 1 < NEDGE);
    if (is64) {
        d0 = ei[2 * (NEDGE + e)];
        s0 = ei[2 * e];
        if (has1) { d1 = ei[2 * (NEDGE + e) + 2]; s1 = ei[2 * e + 2]; }
    } else {
        d0 = ei[NEDGE + e];
        s0 = ei[e];
        if (has1) { d1 = ei[NEDGE + e + 1]; s1 = ei[e + 1]; }
    }
    int p0 = atomicAdd(&cursor[d0], 1);
    int p1 = has1 ? atomicAdd(&cursor[d1], 1) : 0;
    unsigned int w0 = f2bf(ldf(ew, f32, e));
    epk[p0] = (w0 << 16) | (unsigned int)s0;
    if (has1) {
        unsigned int w1 = f2bf(ldf(ew, f32, e + 1));
        epk[p1] = (w1 << 16) | (unsigned int)s1;
    }
}

// ---- k_first: lin1(64x256) + in-reg LN0(half1) + gemm(cw0) -> z0 (round-7 body) ----
__global__ __launch_bounds__(256, 5) void k_first(
    const void* __restrict__ x,
    const unsigned short* __restrict__ w1t,   // pre-swizzled [256][128]
    const float* __restrict__ b1f,
    const float* __restrict__ ngf, const float* __restrict__ nbf,
    const unsigned short* __restrict__ cw0,   // pre-swizzled [128][128]
    const int* __restrict__ flags,
    unsigned short* __restrict__ h,
    unsigned short* __restrict__ z0)
{
    __shared__ __align__(16) unsigned short xb[64 * 128];    // 16KB; reused as a_tile
    __shared__ __align__(16) unsigned short wt[64 * 128];    // 16KB weight stage
    int t = threadIdx.x;
    int r0 = blockIdx.x * 64;
    int f32x = flags[1];
    int w = t >> 6, lane = t & 63, quad = lane >> 4, ln = lane & 15;
    const f32x4 zf = {0.f, 0.f, 0.f, 0.f};

#pragma unroll
    for (int i = 0; i < 4; i++) {
        int cb = (i * 256 + t) * 16;
        gload_lds16((const char*)w1t + cb, (char*)wt + cb);
    }
#pragma unroll
    for (int i = 0; i < 4; i++) {
        int chunk = i * 256 + t;
        int row = chunk >> 4, c16 = chunk & 15;
        int grow = r0 + row;
        u16x8 val = {0, 0, 0, 0, 0, 0, 0, 0};
        if (grow < NN) {
            if (f32x) {
                const float* p = (const float*)x + (long long)grow * INC + c16 * 8;
                float4 a = *(const float4*)p;
                float4 c = *(const float4*)(p + 4);
                val[0] = f2bf(a.x); val[1] = f2bf(a.y); val[2] = f2bf(a.z); val[3] = f2bf(a.w);
                val[4] = f2bf(c.x); val[5] = f2bf(c.y); val[6] = f2bf(c.z); val[7] = f2bf(c.w);
            } else {
                val = *(const u16x8*)((const unsigned short*)x + (long long)grow * INC + c16 * 8);
            }
        }
        *(u16x8*)((char*)xb + row * 256 + ((c16 * 16) ^ ((row & 7) << 4))) = val;
    }
    __syncthreads();

    f32x4 acc[2][8];
#pragma unroll
    for (int i = 0; i < 2; i++)
#pragma unroll
        for (int j = 0; j < 8; j++) acc[i][j] = zf;

#pragma unroll
    for (int ph = 0; ph < 4; ph++) {
        int nh = ph >> 1, s = ph & 1;
#pragma unroll
        for (int kk = 0; kk < 4; kk++) {
            int cb = kk * 64 + quad * 16;
            int rA = w * 16 + ln;
            bf16x8 a = *(const bf16x8*)((const char*)xb + rA * 256 + (cb ^ ((rA & 7) << 4)));
#pragma unroll
            for (int nfl = 0; nfl < 4; nfl++) {
                int rB = nfl * 16 + ln;
                bf16x8 b = *(const bf16x8*)((const char*)wt + rB * 256 + (cb ^ ((rB & 7) << 4)));
                acc[nh][s * 4 + nfl] =
                    __builtin_amdgcn_mfma_f32_16x16x32_bf16(a, b, acc[nh][s * 4 + nfl], 0, 0, 0);
            }
        }
        __syncthreads();
        if (ph < 3) {
#pragma unroll
            for (int i = 0; i < 4; i++) {
                int cb = (i * 256 + t) * 16;
                gload_lds16((const char*)w1t + (ph + 1) * 16384 + cb, (char*)wt + cb);
            }
            __syncthreads();
        }
    }

#pragma unroll
    for (int i = 0; i < 4; i++) {
        int cb = (i * 256 + t) * 16;
        gload_lds16((const char*)cw0 + cb, (char*)wt + cb);
    }

    float ga8[8], be8[8], yv[8][4];
#pragma unroll
    for (int nf = 0; nf < 8; nf++) {
        int col = nf * 16 + ln;
        float b0 = b1f[col], b1 = b1f[128 + col];
        ga8[nf] = ngf[col]; be8[nf] = nbf[col];
#pragma unroll
        for (int r4 = 0; r4 < 4; r4++) {
            int row = r0 + w * 16 + quad * 4 + r4;
            unsigned short h0 = f2bf(acc[0][nf][r4] + b0);
            unsigned short h1 = f2bf(acc[1][nf][r4] + b1);
            if (row < NN) {
                h[(long long)row * HIDC + col] = h0;
                h[(long long)row * HIDC + 128 + col] = h1;
            }
            yv[nf][r4] = bf2f(h1);
        }
    }
    unsigned short* a_tile = xb;
#pragma unroll
    for (int r4 = 0; r4 < 4; r4++) {
        float s = 0.f, q = 0.f;
#pragma unroll
        for (int nf = 0; nf < 8; nf++) { s += yv[nf][r4]; q += yv[nf][r4] * yv[nf][r4]; }
        s += __shfl_xor(s, 1, 64); s += __shfl_xor(s, 2, 64);
        s += __shfl_xor(s, 4, 64); s += __shfl_xor(s, 8, 64);
        q += __shfl_xor(q, 1, 64); q += __shfl_xor(q, 2, 64);
        q += __shfl_xor(q, 4, 64); q += __shfl_xor(q, 8, 64);
        float mu = s * (1.0f / GCH);
        float var = q * (1.0f / GCH) - mu * mu;
        float rs = rsqrtf(var + EPSV);
        int row = w * 16 + quad * 4 + r4;
#pragma unroll
        for (int nf = 0; nf < 8; nf++) {
            float val = (yv[nf][r4] - mu) * rs * ga8[nf] + be8[nf];
            if (val < 0.f) val = 0.f;
            *(unsigned short*)((char*)a_tile + row * 256 +
                               (((nf * 16 + ln) * 2) ^ ((row & 7) << 4))) = f2bf(val);
        }
    }
    __syncthreads();

    f32x4 acc2[8];
#pragma unroll
    for (int j = 0; j < 8; j++) acc2[j] = zf;
#pragma unroll
    for (int s = 0; s < 2; s++) {
#pragma unroll
        for (int kk = 0; kk < 4; kk++) {
            int cb = kk * 64 + quad * 16;
            int rA = w * 16 + ln;
            bf16x8 a = *(const bf16x8*)((const char*)a_tile + rA * 256 + (cb ^ ((rA & 7) << 4)));
#pragma unroll
            for (int nfl = 0; nfl < 4; nfl++) {
                int rB = nfl * 16 + ln;
                bf16x8 b = *(const bf16x8*)((const char*)wt + rB * 256 + (cb ^ ((rB & 7) << 4)));
                acc2[s * 4 + nfl] =
                    __builtin_amdgcn_mfma_f32_16x16x32_bf16(a, b, acc2[s * 4 + nfl], 0, 0, 0);
            }
        }
        if (s == 0) {
            __syncthreads();
#pragma unroll
            for (int i = 0; i < 4; i++) {
                int cb = (i * 256 + t) * 16;
                gload_lds16((const char*)cw0 + 16384 + cb, (char*)wt + cb);
            }
            __syncthreads();
        }
    }
#pragma unroll
    for (int nf = 0; nf < 8; nf++) {
        int col = nf * 16 + ln;
#pragma unroll
        for (int r4 = 0; r4 < 4; r4++) {
            int row2 = r0 + w * 16 + quad * 4 + r4;
            if (row2 < NN) z0[(long long)row2 * GCH + col] = f2bf(acc2[nf][r4]);
        }
    }
}

// ---- k_fused (512 threads, 8 waves): agg (2 node-iterations) + LN -> LDS
//      + 8-wave gemm (full 32KB cw staged under agg). 48KB LDS -> 3 blocks/CU.
__global__ __launch_bounds__(512, 6) void k_fused(
    const int* __restrict__ rowptr, const unsigned int* __restrict__ epk,
    const unsigned short* __restrict__ zin,
    const float* __restrict__ cb,
    unsigned short* __restrict__ h, int out_half,
    const float* __restrict__ ga, const float* __restrict__ be,
    const unsigned short* __restrict__ cwn,   // pre-swizzled [128][128]
    unsigned short* __restrict__ zout)
{
    __shared__ __align__(16) unsigned short wt[128 * 128];    // 32KB full cw
    __shared__ __align__(16) unsigned short a_tile[64 * 128]; // 16KB
    int t = threadIdx.x;
    int r0 = blockIdx.x * 64;
    int c8 = (t & 15) << 3;

    // stage full cw (latency hides under agg)
#pragma unroll
    for (int i = 0; i < 4; i++) {
        int cbyte = (i * 512 + t) * 16;
        gload_lds16((const char*)cwn + cbyte, (char*)wt + cbyte);
    }

    int begA[2], endA[2];
#pragma unroll
    for (int bt = 0; bt < 2; bt++) {
        int node = r0 + bt * 32 + (t >> 4);
        begA[bt] = (node < NN) ? rowptr[node] : 0;
        endA[bt] = (node < NN) ? rowptr[node + 1] : 0;
    }

#pragma unroll 1
    for (int bt = 0; bt < 2; bt++) {
        int row = bt * 32 + (t >> 4);
        int node = r0 + row;
        if (node < NN) {
            int beg = begA[bt], end = endA[bt];
            unsigned short* hp = h + (long long)node * HIDC + out_half * GCH + c8;
            u16x8 hv = *(u16x8*)hp;
            const unsigned short* zb = zin + c8;
            float acc[8];
#pragma unroll
            for (int j = 0; j < 8; j++) acc[j] = 0.f;

            int e = beg;
            for (; e + 7 < end; e += 8) {
                unsigned int pe[8];
                u16x8 v[8];
#pragma unroll
                for (int i = 0; i < 8; i++) pe[i] = epk[e + i];
#pragma unroll
                for (int i = 0; i < 8; i++)
                    v[i] = *(const u16x8*)(zb + (long long)(pe[i] & 0xFFFFu) * GCH);
#pragma unroll
                for (int i = 0; i < 8; i++) {
                    float wv = bf2f((unsigned short)(pe[i] >> 16));
#pragma unroll
                    for (int j = 0; j < 8; j++) acc[j] += wv * bf2f(v[i][j]);
                }
            }
            if (e + 3 < end) {
                unsigned int pe[4];
                u16x8 v[4];
#pragma unroll
                for (int i = 0; i < 4; i++) pe[i] = epk[e + i];
#pragma unroll
                for (int i = 0; i < 4; i++)
                    v[i] = *(const u16x8*)(zb + (long long)(pe[i] & 0xFFFFu) * GCH);
#pragma unroll
                for (int i = 0; i < 4; i++) {
                    float wv = bf2f((unsigned short)(pe[i] >> 16));
#pragma unroll
                    for (int j = 0; j < 8; j++) acc[j] += wv * bf2f(v[i][j]);
                }
                e += 4;
            }
            for (; e < end; e++) {
                unsigned int pe = epk[e];
                float w0 = bf2f((unsigned short)(pe >> 16));
                u16x8 v = *(const u16x8*)(zb + (long long)(pe & 0xFFFFu) * GCH);
#pragma unroll
                for (int j = 0; j < 8; j++) acc[j] += w0 * bf2f(v[j]);
            }

            float y[8]; float sum = 0.f, sq = 0.f;
#pragma unroll
            for (int j = 0; j < 8; j++) {
                float yy = bf2f(hv[j]) + acc[j] + cb[c8 + j];
                unsigned short r = f2bf(yy);
                hv[j] = r;
                y[j] = bf2f(r);
                sum += y[j]; sq += y[j] * y[j];
            }
            *(u16x8*)hp = hv;

            sum += __shfl_xor(sum, 1, 64); sum += __shfl_xor(sum, 2, 64);
            sum += __shfl_xor(sum, 4, 64); sum += __shfl_xor(sum, 8, 64);
            sq  += __shfl_xor(sq, 1, 64);  sq  += __shfl_xor(sq, 2, 64);
            sq  += __shfl_xor(sq, 4, 64);  sq  += __shfl_xor(sq, 8, 64);
            float mu = sum * (1.0f / GCH);
            float var = sq * (1.0f / GCH) - mu * mu;
            float rs = rsqrtf(var + EPSV);
            u16x8 o;
#pragma unroll
            for (int j = 0; j < 8; j++) {
                float val = (y[j] - mu) * rs * ga[c8 + j] + be[c8 + j];
                if (val < 0.f) val = 0.f;
                o[j] = f2bf(val);
            }
            *(u16x8*)((char*)a_tile + row * 256 + ((c8 * 2) ^ ((row & 7) << 4))) = o;
        }
    }
    __syncthreads();

    // gemm: 8 waves, wave = (col-half ch, row-group wr)
    int w = t >> 6, lane = t & 63, quad = lane >> 4, ln = lane & 15;
    int wr = w & 3, ch = w >> 2;
    const f32x4 zf = {0.f, 0.f, 0.f, 0.f};
    f32x4 acc2[4];
#pragma unroll
    for (int j = 0; j < 4; j++) acc2[j] = zf;
#pragma unroll
    for (int kk = 0; kk < 4; kk++) {
        int cbyte = kk * 64 + quad * 16;
        int rA = wr * 16 + ln;
        bf16x8 a = *(const bf16x8*)((const char*)a_tile + rA * 256 + (cbyte ^ ((rA & 7) << 4)));
#pragma unroll
        for (int nfl = 0; nfl < 4; nfl++) {
            int rB = ch * 64 + nfl * 16 + ln;
            bf16x8 b = *(const bf16x8*)((const char*)wt + rB * 256 + (cbyte ^ ((rB & 7) << 4)));
            acc2[nfl] = __builtin_amdgcn_mfma_f32_16x16x32_bf16(a, b, acc2[nfl], 0, 0, 0);
        }
    }
#pragma unroll
    for (int nfl = 0; nfl < 4; nfl++) {
        int col = ch * 64 + nfl * 16 + ln;
#pragma unroll
        for (int r4 = 0; r4 < 4; r4++) {
            int row2 = r0 + wr * 16 + quad * 4 + r4;
            if (row2 < NN) zout[(long long)row2 * GCH + col] = f2bf(acc2[nfl][r4]);
        }
    }
}

// ---- k_last (512 threads): agg(7) + final LN(256) -> LDS + gemm(W2, waves 0-3) ----
__global__ __launch_bounds__(512, 6) void k_last(
    const int* __restrict__ rowptr, const unsigned int* __restrict__ epk,
    const unsigned short* __restrict__ zin,
    const float* __restrict__ cb,
    unsigned short* __restrict__ h,
    const float* __restrict__ fgf, const float* __restrict__ fbf,
    const unsigned short* __restrict__ w2t,   // pre-swizzled [48][256]
    const float* __restrict__ b2f,
    const int* __restrict__ flags,
    void* __restrict__ out)
{
    __shared__ __align__(16) unsigned short a_tile[64 * 256];   // 32KB
    int t = threadIdx.x;
    int r0 = blockIdx.x * 64;
    int c8 = (t & 15) << 3;
    const int out_half = 1;

    int begA[2], endA[2];
#pragma unroll
    for (int bt = 0; bt < 2; bt++) {
        int node = r0 + bt * 32 + (t >> 4);
        begA[bt] = (node < NN) ? rowptr[node] : 0;
        endA[bt] = (node < NN) ? rowptr[node + 1] : 0;
    }

#pragma unroll 1
    for (int bt = 0; bt < 2; bt++) {
        int row = bt * 32 + (t >> 4);
        int node = r0 + row;
        if (node < NN) {
            int beg = begA[bt], end = endA[bt];
            unsigned short* hp = h + (long long)node * HIDC + out_half * GCH + c8;
            u16x8 hv = *(u16x8*)hp;
            const unsigned short* zb = zin + c8;
            float acc[8];
#pragma unroll
            for (int j = 0; j < 8; j++) acc[j] = 0.f;

            int e = beg;
            for (; e + 7 < end; e += 8) {
                unsigned int pe[8];
                u16x8 v[8];
#pragma unroll
                for (int i = 0; i < 8; i++) pe[i] = epk[e + i];
#pragma unroll
                for (int i = 0; i < 8; i++)
                    v[i] = *(const u16x8*)(zb + (long long)(pe[i] & 0xFFFFu) * GCH);
#pragma unroll
                for (int i = 0; i < 8; i++) {
                    float wv = bf2f((unsigned short)(pe[i] >> 16));
#pragma unroll
                    for (int j = 0; j < 8; j++) acc[j] += wv * bf2f(v[i][j]);
                }
            }
            if (e + 3 < end) {
                unsigned int pe[4];
                u16x8 v[4];
#pragma unroll
                for (int i = 0; i < 4; i++) pe[i] = epk[e + i];
#pragma unroll
                for (int i = 0; i < 4; i++)
                    v[i] = *(const u16x8*)(zb + (long long)(pe[i] & 0xFFFFu) * GCH);
#pragma unroll
                for (int i = 0; i < 4; i++) {
                    float wv = bf2f((unsigned short)(pe[i] >> 16));
#pragma unroll
                    for (int j = 0; j < 8; j++) acc[j] += wv * bf2f(v[i][j]);
                }
                e += 4;
            }
            for (; e < end; e++) {
                unsigned int pe = epk[e];
                float w0 = bf2f((unsigned short)(pe >> 16));
                u16x8 v = *(const u16x8*)(zb + (long long)(pe & 0xFFFFu) * GCH);
#pragma unroll
                for (int j = 0; j < 8; j++) acc[j] += w0 * bf2f(v[j]);
            }

            float y[8]; float sum = 0.f, sq = 0.f;
#pragma unroll
            for (int j = 0; j < 8; j++) {
                float yy = bf2f(hv[j]) + acc[j] + cb[c8 + j];
                unsigned short r = f2bf(yy);
                hv[j] = r;
                y[j] = bf2f(r);
                sum += y[j]; sq += y[j] * y[j];
            }
            *(u16x8*)hp = hv;

            float oy[8];
            u16x8 ov = *(const u16x8*)(h + (long long)node * HIDC + (out_half ^ 1) * GCH + c8);
#pragma unroll
            for (int j = 0; j < 8; j++) {
                oy[j] = bf2f(ov[j]);
                sum += oy[j]; sq += oy[j] * oy[j];
            }
            sum += __shfl_xor(sum, 1, 64); sum += __shfl_xor(sum, 2, 64);
            sum += __shfl_xor(sum, 4, 64); sum += __shfl_xor(sum, 8, 64);
            sq  += __shfl_xor(sq, 1, 64);  sq  += __shfl_xor(sq, 2, 64);
            sq  += __shfl_xor(sq, 4, 64);  sq  += __shfl_xor(sq, 8, 64);
            float mu = sum * (1.0f / HIDC);
            float var = sq * (1.0f / HIDC) - mu * mu;
            float rs = rsqrtf(var + EPSV);

            u16x8 o;
            int cn = out_half * GCH + c8;
#pragma unroll
            for (int j = 0; j < 8; j++) {
                float val = (y[j] - mu) * rs * fgf[cn + j] + fbf[cn + j];
                if (val < 0.f) val = 0.f;
                o[j] = f2bf(val);
            }
            *(u16x8*)((char*)a_tile + row * 512 + ((cn * 2) ^ ((row & 7) << 4))) = o;
            int co = (out_half ^ 1) * GCH + c8;
#pragma unroll
            for (int j = 0; j < 8; j++) {
                float val = (oy[j] - mu) * rs * fgf[co + j] + fbf[co + j];
                if (val < 0.f) val = 0.f;
                o[j] = f2bf(val);
            }
            *(u16x8*)((char*)a_tile + row * 512 + ((co * 2) ^ ((row & 7) << 4))) = o;
        }
    }
    __syncthreads();

    int w = t >> 6, lane = t & 63, quad = lane >> 4, ln = lane & 15;
    if (w < 4) {
        const f32x4 zf = {0.f, 0.f, 0.f, 0.f};
        f32x4 acc2[3];
#pragma unroll
        for (int j = 0; j < 3; j++) acc2[j] = zf;
#pragma unroll
        for (int kk = 0; kk < 8; kk++) {
            int cbyte = kk * 64 + quad * 16;
            int ko = kk * 32 + quad * 8;
            int row = w * 16 + ln;
            bf16x8 a = *(const bf16x8*)((const char*)a_tile + row * 512 + (cbyte ^ ((row & 7) << 4)));
#pragma unroll
            for (int nf = 0; nf < 3; nf++) {
                int rB = nf * 16 + ln;
                bf16x8 b = ld8(w2t + rB * 256 + (ko ^ ((rB & 7) << 3)));
                acc2[nf] = __builtin_amdgcn_mfma_f32_16x16x32_bf16(a, b, acc2[nf], 0, 0, 0);
            }
        }
        int f32o = flags[1];
#pragma unroll
        for (int nf = 0; nf < 3; nf++) {
            int col = nf * 16 + ln;
            if (col >= OUTC) continue;
            float bias = b2f[col];
#pragma unroll
            for (int r4 = 0; r4 < 4; r4++) {
                int row2 = r0 + w * 16 + quad * 4 + r4;
                if (row2 < NN) {
                    float val = acc2[nf][r4] + bias;
                    long long o = (long long)row2 * OUTC + col;
                    if (f32o) ((float*)out)[o] = val;
                    else      ((unsigned short*)out)[o] = f2bf(val);
                }
            }
        }
    }
}

extern "C" void kernel_launch(void* const* d_in, const int* in_sizes, int n_in,
                              void* d_out, int out_size, void* d_ws, size_t ws_size,
                              hipStream_t stream)
{
    const void* x       = d_in[0];
    const int*  ei      = (const int*)d_in[1];
    const void* ew      = d_in[2];
    const void* lin1_w  = d_in[3];
    const void* lin1_b  = d_in[4];
    const void* lin2_w  = d_in[5];
    const void* lin2_b  = d_in[6];
    const void* norm_g  = d_in[7];
    const void* norm_b  = d_in[8];
    const void* conv_w  = d_in[9];
    const void* conv_b  = d_in[10];
    const void* fnorm_g = d_in[11];
    const void* fnorm_b = d_in[12];

    char* ws = (char*)d_ws;
    size_t off = 0;
    auto alloc = [&](size_t bytes) { void* p = (void*)(ws + off); off += (bytes + 255) & ~255ull; return p; };

    unsigned short* h      = (unsigned short*)alloc((size_t)NN * HIDC * 2);
    unsigned short* z0     = (unsigned short*)alloc((size_t)NN * GCH * 2);
    unsigned short* z1     = (unsigned short*)alloc((size_t)NN * GCH * 2);
    unsigned short* w1t    = (unsigned short*)alloc((size_t)CVT_W1 * 2);
    unsigned short* cwt    = (unsigned short*)alloc((size_t)CVT_CW * 2);
    unsigned short* w2t    = (unsigned short*)alloc((size_t)CVT_W2 * 2);
    float*          b1f    = (float*)alloc(256 * 4);
    float*          ngf    = (float*)alloc(1024 * 4);
    float*          nbf    = (float*)alloc(1024 * 4);
    float*          cbf    = (float*)alloc(1024 * 4);
    float*          fgf    = (float*)alloc(256 * 4);
    float*          fbf    = (float*)alloc(256 * 4);
    float*          b2f    = (float*)alloc(48 * 4);
    int*            deg    = (int*)alloc((size_t)NN * 4);
    int*            rowptr = (int*)alloc(((size_t)NN + 1) * 4);
    int*            cursor = (int*)alloc((size_t)NN * 4);
    unsigned int*   epk    = (unsigned int*)alloc((size_t)NEDGE * 4);
    int*            flags  = (int*)alloc(256);

    if (ws_size < off || n_in < 13) {
        float mv = 100.0f + (float)(ws_size >> 20) + ((n_in < 13) ? 10000.0f : 0.0f);
        k_marker<<<(out_size + 255) / 256, 256, 0, stream>>>(d_out, mv, out_size);
        return;
    }

    k_prep<<<885, 256, 0, stream>>>(x, ei, lin1_w, conv_w, lin2_w,
                                    lin1_b, norm_g, norm_b, conv_b,
                                    fnorm_g, fnorm_b, lin2_b,
                                    flags, deg, w1t, cwt, w2t,
                                    b1f, ngf, nbf, cbf, fgf, fbf, b2f);
    k_count<<<(NEDGE / 2 + 255) / 256, 256, 0, stream>>>(ei, flags, deg);
    k_scan<<<SCAN_B, 256, 0, stream>>>(deg, rowptr, cursor);
    k_fill<<<(NEDGE / 2 + 255) / 256, 256, 0, stream>>>(ei, ew, flags, cursor, epk);

    const int GB = (NN + 63) / 64;   // 782
    k_first<<<GB, 256, 0, stream>>>(x, w1t, b1f, ngf, nbf, cwt, flags, h, z0);
    for (int lg = 0; lg < NL * NG - 1; lg++) {
        unsigned short* zin  = (lg & 1) ? z1 : z0;
        unsigned short* zout = (lg & 1) ? z0 : z1;
        k_fused<<<GB, 512, 0, stream>>>(rowptr, epk, zin, cbf + lg * GCH, h, lg & 1,
                                        ngf + (lg + 1) * GCH, nbf + (lg + 1) * GCH,
                                        cwt + (size_t)(lg + 1) * 16384, zout);
    }
    k_last<<<GB, 512, 0, stream>>>(rowptr, epk, z1, cbf + 7 * GCH, h,
                                   fgf, fbf, w2t, b2f, flags, d_out);
}

// Round 10
// 463.783 us; speedup vs baseline: 1.2870x; 1.2870x over previous
//
#include <hip/hip_runtime.h>
#include <stdint.h>

#define NN    50000
#define INC   128
#define HIDC  256
#define OUTC  40
#define GCH   128
#define NL    4
#define NG    2
#define NEDGE 600000
#define EPSV  1e-5f

typedef __bf16 bf16x8 __attribute__((ext_vector_type(8)));
typedef float  f32x4  __attribute__((ext_vector_type(4)));
typedef unsigned short u16x4 __attribute__((ext_vector_type(4)));
typedef unsigned short u16x8 __attribute__((ext_vector_type(8)));

__device__ __forceinline__ float bf2f(unsigned short u) {
    union { float f; unsigned int i; } v;
    v.i = ((unsigned int)u) << 16;
    return v.f;
}
__device__ __forceinline__ unsigned short f2bf(float f) {
    union { float f; unsigned int i; } v;
    v.f = f;
    unsigned int u = v.i;
    u += 0x7FFFu + ((u >> 16) & 1u);   // RNE
    return (unsigned short)(u >> 16);
}
__device__ __forceinline__ float ldf(const void* p, int is_f32, long long i) {
    if (is_f32) return ((const float*)p)[i];
    return bf2f(((const unsigned short*)p)[i]);
}
__device__ __forceinline__ bf16x8 ld8(const unsigned short* p) {
    return *(const bf16x8*)p;
}
// async global->LDS, 16B/lane. Dest is wave-base + lane*16 (linear pattern).
__device__ __forceinline__ void gload_lds16(const void* g, void* l) {
    __builtin_amdgcn_global_load_lds(
        (const __attribute__((address_space(1))) unsigned int*)g,
        (__attribute__((address_space(3))) unsigned int*)l,
        16, 0, 0);
}

// ---- diagnostic marker ----
__global__ void k_marker(void* out, float val, int n) {
    int i = blockIdx.x * 256 + threadIdx.x;
    if (i < n) ((unsigned short*)out)[i] = f2bf(val);
}

// ---- zero deg + detect dtypes ----
__global__ void k_detect(const int* ei, const unsigned short* xprobe,
                         int* flags, int* deg) {
    int t = threadIdx.x;
    int gid = blockIdx.x * 256 + t;
    if (gid < NN) deg[gid] = 0;
    if (blockIdx.x == 0) {
        __shared__ int hi_or, wild_cnt;
        if (t == 0) { hi_or = 0; wild_cnt = 0; }
        __syncthreads();
        int acc = 0;
        for (int i = 0; i < 8; i++) acc |= ei[2 * (t + i * 256) + 1];
        if (acc) atomicOr(&hi_or, 1);
        int wild = 0;
        for (int i = 0; i < 2; i++) {
            unsigned short u = xprobe[t + i * 256];
            int e = (u >> 7) & 0xFF;
            if (e <= 0x30 || e >= 0xC0) wild++;
        }
        atomicAdd(&wild_cnt, wild);
        __syncthreads();
        if (t == 0) {
            flags[0] = hi_or ? 0 : 1;           // 1 => int64 edge_index
            flags[1] = (wild_cnt > 32) ? 1 : 0; // 1 => fp32 float tensors
        }
    }
}

// ---- one-time convert: weights transposed to [n][k] bf16 AND XOR-swizzled
//      (element k ^ ((n&7)<<3)) so kernels stage with LINEAR global_load_lds
//      and read fragments conflict-free.
#define CVT_W1  32768
#define CVT_CW  131072
#define CVT_W2  12288
#define CVT_TOT (CVT_W1 + CVT_CW + CVT_W2)

__global__ void k_convert(const void* w1, const void* cw, const void* w2,
                          const void* b1, const void* ng, const void* nb, const void* cb,
                          const void* fg, const void* fb, const void* b2,
                          const int* flags,
                          unsigned short* w1t, unsigned short* cwt, unsigned short* w2t,
                          float* b1f, float* ngf, float* nbf, float* cbf,
                          float* fgf, float* fbf, float* b2f) {
    int t = threadIdx.x;
    int f32 = flags[1];
    if (blockIdx.x == gridDim.x - 1) {          // params
        b1f[t] = ldf(b1, f32, t);
        fgf[t] = ldf(fg, f32, t);
        fbf[t] = ldf(fb, f32, t);
        if (t < 48) b2f[t] = (t < OUTC) ? ldf(b2, f32, t) : 0.0f;
        for (int i = 0; i < 4; i++) {
            int j = t + i * 256;
            ngf[j] = ldf(ng, f32, j);
            nbf[j] = ldf(nb, f32, j);
            cbf[j] = ldf(cb, f32, j);
        }
        return;
    }
    long long j = (long long)blockIdx.x * 256 + t;
    if (j >= CVT_TOT) return;
    if (j < CVT_W1) {
        int n = (int)(j >> 7), k = (int)(j & 127);
        w1t[n * 128 + (k ^ ((n & 7) << 3))] = f2bf(ldf(w1, f32, (long long)k * HIDC + n));
    } else if (j < CVT_W1 + CVT_CW) {
        long long jj = j - CVT_W1;
        int lg = (int)(jj >> 14);
        int rem = (int)(jj & 16383);
        int n = rem >> 7, k = rem & 127;
        cwt[lg * 16384 + n * 128 + (k ^ ((n & 7) << 3))] =
            f2bf(ldf(cw, f32, (long long)lg * GCH * GCH + (long long)k * GCH + n));
    } else {
        long long jj = j - (CVT_W1 + CVT_CW);
        int n = (int)(jj >> 8), k = (int)(jj & 255);
        w2t[n * 256 + (k ^ ((n & 7) << 3))] =
            (n < OUTC) ? f2bf(ldf(w2, f32, (long long)k * OUTC + n)) : (unsigned short)0;
    }
}

// ---- CSR build ----
__global__ void k_count(const int* __restrict__ ei, const int* __restrict__ flags,
                        int* __restrict__ deg) {
    int e = (blockIdx.x * 256 + threadIdx.x) * 2;
    if (e >= NEDGE) return;
    int d0, d1;
    if (flags[0]) {
        int4 v = *(const int4*)(ei + 2 * (NEDGE + e));
        d0 = v.x; d1 = v.z;
    } else {
        int2 v = *(const int2*)(ei + NEDGE + e);
        d0 = v.x; d1 = v.y;
    }
    atomicAdd(&deg[d0], 1);
    if (e + 1 < NEDGE) atomicAdd(&deg[d1], 1);
}

#define SCAN_B 49
__global__ void k_scan_a(const int* __restrict__ deg, int* __restrict__ bsum) {
    __shared__ int part[256];
    int b = blockIdx.x, t = threadIdx.x;
    int base = b * 1024 + t * 4;
    int s = 0;
#pragma unroll
    for (int j = 0; j < 4; j++) {
        int i = base + j;
        if (i < NN) s += deg[i];
    }
    part[t] = s;
    __syncthreads();
    for (int off = 128; off > 0; off >>= 1) {
        if (t < off) part[t] += part[t + off];
        __syncthreads();
    }
    if (t == 0) bsum[b] = part[0];
}

__global__ void k_scan_c(const int* __restrict__ deg, const int* __restrict__ bsum,
                         int* __restrict__ rowptr, int* __restrict__ cursor) {
    __shared__ int part[256];
    __shared__ int bbase;
    int b = blockIdx.x, t = threadIdx.x;
    if (t == 0) { int r = 0; for (int i = 0; i < b; i++) r += bsum[i]; bbase = r; }
    int base = b * 1024 + t * 4;
    int v[4];
    int s = 0;
#pragma unroll
    for (int j = 0; j < 4; j++) {
        int i = base + j;
        v[j] = (i < NN) ? deg[i] : 0;
        s += v[j];
    }
    part[t] = s;
    __syncthreads();
    for (int off = 1; off < 256; off <<= 1) {
        int x = (t >= off) ? part[t - off] : 0;
        __syncthreads();
        part[t] += x;
        __syncthreads();
    }
    int run = bbase + part[t] - s;
#pragma unroll
    for (int j = 0; j < 4; j++) {
        int i = base + j;
        if (i < NN) { rowptr[i] = run; cursor[i] = run; }
        run += v[j];
    }
    if (b == SCAN_B - 1 && t == 255) rowptr[NN] = NEDGE;
}

// packed fill: ONE 4B store per edge — (bf16 weight << 16) | src (src < 65536)
__global__ void k_fill(const int* __restrict__ ei, const void* __restrict__ ew,
                       const int* __restrict__ flags,
                       int* __restrict__ cursor, unsigned int* __restrict__ epk) {
    int e = (blockIdx.x * 256 + threadIdx.x) * 2;
    if (e >= NEDGE) return;
    int is64 = flags[0];
    int f32 = flags[1];
    int d0, s0, d1 = 0, s1 = 0;
    int has1 = (e + 1 < NEDGE);
    if (is64) {
        d0 = ei[2 * (NEDGE + e)];
        s0 = ei[2 * e];
        if (has1) { d1 = ei[2 * (NEDGE + e) + 2]; s1 = ei[2 * e + 2]; }
    } else {
        d0 = ei[NEDGE + e];
        s0 = ei[e];
        if (has1) { d1 = ei[NEDGE + e + 1]; s1 = ei[e + 1]; }
    }
    int p0 = atomicAdd(&cursor[d0], 1);
    int p1 = has1 ? atomicAdd(&cursor[d1], 1) : 0;
    unsigned int w0 = f2bf(ldf(ew, f32, e));
    epk[p0] = (w0 << 16) | (unsigned int)s0;
    if (has1) {
        unsigned int w1 = f2bf(ldf(ew, f32, e + 1));
        epk[p1] = (w1 << 16) | (unsigned int)s1;
    }
}

// ---- k_first: lin1(64x256) + in-reg LN0(half1) + gemm(cw0) -> z0.
//      32KB LDS total (16KB x-tile + 16KB weight stage) -> 5 blocks/CU.
__global__ __launch_bounds__(256, 5) void k_first(
    const void* __restrict__ x,
    const unsigned short* __restrict__ w1t,   // pre-swizzled [256][128]
    const float* __restrict__ b1f,
    const float* __restrict__ ngf, const float* __restrict__ nbf,
    const unsigned short* __restrict__ cw0,   // pre-swizzled [128][128]
    const int* __restrict__ flags,
    unsigned short* __restrict__ h,
    unsigned short* __restrict__ z0)
{
    __shared__ __align__(16) unsigned short xb[64 * 128];    // 16KB; reused as a_tile
    __shared__ __align__(16) unsigned short wt[64 * 128];    // 16KB weight stage
    int t = threadIdx.x;
    int r0 = blockIdx.x * 64;
    int f32x = flags[1];
    int w = t >> 6, lane = t & 63, quad = lane >> 4, ln = lane & 15;
    const f32x4 zf = {0.f, 0.f, 0.f, 0.f};

    // stage w1 chunk 0 (rows 0..63), async
#pragma unroll
    for (int i = 0; i < 4; i++) {
        int cb = (i * 256 + t) * 16;
        gload_lds16((const char*)w1t + cb, (char*)wt + cb);
    }
    // reg-stage x tile -> xb, swizzled
#pragma unroll
    for (int i = 0; i < 4; i++) {
        int chunk = i * 256 + t;
        int row = chunk >> 4, c16 = chunk & 15;
        int grow = r0 + row;
        u16x8 val = {0, 0, 0, 0, 0, 0, 0, 0};
        if (grow < NN) {
            if (f32x) {
                const float* p = (const float*)x + (long long)grow * INC + c16 * 8;
                float4 a = *(const float4*)p;
                float4 c = *(const float4*)(p + 4);
                val[0] = f2bf(a.x); val[1] = f2bf(a.y); val[2] = f2bf(a.z); val[3] = f2bf(a.w);
                val[4] = f2bf(c.x); val[5] = f2bf(c.y); val[6] = f2bf(c.z); val[7] = f2bf(c.w);
            } else {
                val = *(const u16x8*)((const unsigned short*)x + (long long)grow * INC + c16 * 8);
            }
        }
        *(u16x8*)((char*)xb + row * 256 + ((c16 * 16) ^ ((row & 7) << 4))) = val;
    }
    __syncthreads();

    f32x4 acc[2][8];
#pragma unroll
    for (int i = 0; i < 2; i++)
#pragma unroll
        for (int j = 0; j < 8; j++) acc[i][j] = zf;

    // 4 phases: 64 B-rows each (nh = ph>>1, nf-halves)
#pragma unroll
    for (int ph = 0; ph < 4; ph++) {
        int nh = ph >> 1, s = ph & 1;
#pragma unroll
        for (int kk = 0; kk < 4; kk++) {
            int cb = kk * 64 + quad * 16;
            int rA = w * 16 + ln;
            bf16x8 a = *(const bf16x8*)((const char*)xb + rA * 256 + (cb ^ ((rA & 7) << 4)));
#pragma unroll
            for (int nfl = 0; nfl < 4; nfl++) {
                int rB = nfl * 16 + ln;
                bf16x8 b = *(const bf16x8*)((const char*)wt + rB * 256 + (cb ^ ((rB & 7) << 4)));
                acc[nh][s * 4 + nfl] =
                    __builtin_amdgcn_mfma_f32_16x16x32_bf16(a, b, acc[nh][s * 4 + nfl], 0, 0, 0);
            }
        }
        __syncthreads();                 // wt reads done
        if (ph < 3) {
#pragma unroll
            for (int i = 0; i < 4; i++) {
                int cb = (i * 256 + t) * 16;
                gload_lds16((const char*)w1t + (ph + 1) * 16384 + cb, (char*)wt + cb);
            }
            __syncthreads();
        }
    }

    // stage cw0 chunk 0 (async; consumed after LN)
#pragma unroll
    for (int i = 0; i < 4; i++) {
        int cb = (i * 256 + t) * 16;
        gload_lds16((const char*)cw0 + cb, (char*)wt + cb);
    }

    // epilogue: h stores + rounded half1 values for LN
    float ga8[8], be8[8], yv[8][4];
#pragma unroll
    for (int nf = 0; nf < 8; nf++) {
        int col = nf * 16 + ln;
        float b0 = b1f[col], b1 = b1f[128 + col];
        ga8[nf] = ngf[col]; be8[nf] = nbf[col];
#pragma unroll
        for (int r4 = 0; r4 < 4; r4++) {
            int row = r0 + w * 16 + quad * 4 + r4;
            unsigned short h0 = f2bf(acc[0][nf][r4] + b0);
            unsigned short h1 = f2bf(acc[1][nf][r4] + b1);
            if (row < NN) {
                h[(long long)row * HIDC + col] = h0;
                h[(long long)row * HIDC + 128 + col] = h1;
            }
            yv[nf][r4] = bf2f(h1);
        }
    }
    // in-register LN+ReLU -> a_tile (= xb region; xb reads finished pre-epilogue)
    unsigned short* a_tile = xb;
#pragma unroll
    for (int r4 = 0; r4 < 4; r4++) {
        float s = 0.f, q = 0.f;
#pragma unroll
        for (int nf = 0; nf < 8; nf++) { s += yv[nf][r4]; q += yv[nf][r4] * yv[nf][r4]; }
        s += __shfl_xor(s, 1, 64); s += __shfl_xor(s, 2, 64);
        s += __shfl_xor(s, 4, 64); s += __shfl_xor(s, 8, 64);
        q += __shfl_xor(q, 1, 64); q += __shfl_xor(q, 2, 64);
        q += __shfl_xor(q, 4, 64); q += __shfl_xor(q, 8, 64);
        float mu = s * (1.0f / GCH);
        float var = q * (1.0f / GCH) - mu * mu;
        float rs = rsqrtf(var + EPSV);
        int row = w * 16 + quad * 4 + r4;
#pragma unroll
        for (int nf = 0; nf < 8; nf++) {
            float val = (yv[nf][r4] - mu) * rs * ga8[nf] + be8[nf];
            if (val < 0.f) val = 0.f;
            *(unsigned short*)((char*)a_tile + row * 256 +
                               (((nf * 16 + ln) * 2) ^ ((row & 7) << 4))) = f2bf(val);
        }
    }
    __syncthreads();

    // gemm in 2 N-halves (re-stage cw0 chunk 1 between)
    f32x4 acc2[8];
#pragma unroll
    for (int j = 0; j < 8; j++) acc2[j] = zf;
#pragma unroll
    for (int s = 0; s < 2; s++) {
#pragma unroll
        for (int kk = 0; kk < 4; kk++) {
            int cb = kk * 64 + quad * 16;
            int rA = w * 16 + ln;
            bf16x8 a = *(const bf16x8*)((const char*)a_tile + rA * 256 + (cb ^ ((rA & 7) << 4)));
#pragma unroll
            for (int nfl = 0; nfl < 4; nfl++) {
                int rB = nfl * 16 + ln;
                bf16x8 b = *(const bf16x8*)((const char*)wt + rB * 256 + (cb ^ ((rB & 7) << 4)));
                acc2[s * 4 + nfl] =
                    __builtin_amdgcn_mfma_f32_16x16x32_bf16(a, b, acc2[s * 4 + nfl], 0, 0, 0);
            }
        }
        if (s == 0) {
            __syncthreads();
#pragma unroll
            for (int i = 0; i < 4; i++) {
                int cb = (i * 256 + t) * 16;
                gload_lds16((const char*)cw0 + 16384 + cb, (char*)wt + cb);
            }
            __syncthreads();
        }
    }
#pragma unroll
    for (int nf = 0; nf < 8; nf++) {
        int col = nf * 16 + ln;
#pragma unroll
        for (int r4 = 0; r4 < 4; r4++) {
            int row2 = r0 + w * 16 + quad * 4 + r4;
            if (row2 < NN) z0[(long long)row2 * GCH + col] = f2bf(acc2[nf][r4]);
        }
    }
}

// ---- k_fused: agg over 64 contiguous nodes + residual RMW + LN -> LDS
//      + gemm (cw staged in 2x16KB halves). 32KB LDS -> 5 blocks/CU.
__global__ __launch_bounds__(256, 5) void k_fused(
    const int* __restrict__ rowptr, const unsigned int* __restrict__ epk,
    const unsigned short* __restrict__ zin,
    const float* __restrict__ cb,
    unsigned short* __restrict__ h, int out_half,
    const float* __restrict__ ga, const float* __restrict__ be,
    const unsigned short* __restrict__ cwn,   // pre-swizzled [128][128]
    unsigned short* __restrict__ zout)
{
    __shared__ __align__(16) unsigned short wt[64 * 128];     // 16KB (N-half of cw)
    __shared__ __align__(16) unsigned short a_tile[64 * 128]; // 16KB
    int t = threadIdx.x;
    int r0 = blockIdx.x * 64;
    int c8 = (t & 15) << 3;

    // stage cw N-half 0 (latency hides under agg)
#pragma unroll
    for (int i = 0; i < 4; i++) {
        int cbyte = (i * 256 + t) * 16;
        gload_lds16((const char*)cwn + cbyte, (char*)wt + cbyte);
    }

#pragma unroll 1
    for (int bt = 0; bt < 4; bt++) {
        int row = bt * 16 + (t >> 4);
        int node = r0 + row;
        if (node < NN) {
            int beg = rowptr[node], end = rowptr[node + 1];
            unsigned short* hp = h + (long long)node * HIDC + out_half * GCH + c8;
            u16x8 hv = *(u16x8*)hp;
            const unsigned short* zb = zin + c8;
            float acc[8];
#pragma unroll
            for (int j = 0; j < 8; j++) acc[j] = 0.f;

            int e = beg;
            for (; e + 7 < end; e += 8) {
                unsigned int pe[8];
                u16x8 v[8];
#pragma unroll
                for (int i = 0; i < 8; i++) pe[i] = epk[e + i];
#pragma unroll
                for (int i = 0; i < 8; i++)
                    v[i] = *(const u16x8*)(zb + (long long)(pe[i] & 0xFFFFu) * GCH);
#pragma unroll
                for (int i = 0; i < 8; i++) {
                    float wv = bf2f((unsigned short)(pe[i] >> 16));
#pragma unroll
                    for (int j = 0; j < 8; j++) acc[j] += wv * bf2f(v[i][j]);
                }
            }
            if (e + 3 < end) {
                unsigned int pe[4];
                u16x8 v[4];
#pragma unroll
                for (int i = 0; i < 4; i++) pe[i] = epk[e + i];
#pragma unroll
                for (int i = 0; i < 4; i++)
                    v[i] = *(const u16x8*)(zb + (long long)(pe[i] & 0xFFFFu) * GCH);
#pragma unroll
                for (int i = 0; i < 4; i++) {
                    float wv = bf2f((unsigned short)(pe[i] >> 16));
#pragma unroll
                    for (int j = 0; j < 8; j++) acc[j] += wv * bf2f(v[i][j]);
                }
                e += 4;
            }
            for (; e < end; e++) {
                unsigned int pe = epk[e];
                float w0 = bf2f((unsigned short)(pe >> 16));
                u16x8 v = *(const u16x8*)(zb + (long long)(pe & 0xFFFFu) * GCH);
#pragma unroll
                for (int j = 0; j < 8; j++) acc[j] += w0 * bf2f(v[j]);
            }

            float y[8]; float sum = 0.f, sq = 0.f;
#pragma unroll
            for (int j = 0; j < 8; j++) {
                float yy = bf2f(hv[j]) + acc[j] + cb[c8 + j];
                unsigned short r = f2bf(yy);
                hv[j] = r;
                y[j] = bf2f(r);
                sum += y[j]; sq += y[j] * y[j];
            }
            *(u16x8*)hp = hv;

            sum += __shfl_xor(sum, 1, 64); sum += __shfl_xor(sum, 2, 64);
            sum += __shfl_xor(sum, 4, 64); sum += __shfl_xor(sum, 8, 64);
            sq  += __shfl_xor(sq, 1, 64);  sq  += __shfl_xor(sq, 2, 64);
            sq  += __shfl_xor(sq, 4, 64);  sq  += __shfl_xor(sq, 8, 64);
            float mu = sum * (1.0f / GCH);
            float var = sq * (1.0f / GCH) - mu * mu;
            float rs = rsqrtf(var + EPSV);
            u16x8 o;
#pragma unroll
            for (int j = 0; j < 8; j++) {
                float val = (y[j] - mu) * rs * ga[c8 + j] + be[c8 + j];
                if (val < 0.f) val = 0.f;
                o[j] = f2bf(val);
            }
            *(u16x8*)((char*)a_tile + row * 256 + ((c8 * 2) ^ ((row & 7) << 4))) = o;
        }
    }
    __syncthreads();

    // gemm in 2 N-halves (re-stage wt between)
    int w = t >> 6, lane = t & 63, quad = lane >> 4, ln = lane & 15;
    const f32x4 zf = {0.f, 0.f, 0.f, 0.f};
    f32x4 acc2[8];
#pragma unroll
    for (int j = 0; j < 8; j++) acc2[j] = zf;
#pragma unroll
    for (int s = 0; s < 2; s++) {
#pragma unroll
        for (int kk = 0; kk < 4; kk++) {
            int cbyte = kk * 64 + quad * 16;
            int rA = w * 16 + ln;
            bf16x8 a = *(const bf16x8*)((const char*)a_tile + rA * 256 + (cbyte ^ ((rA & 7) << 4)));
#pragma unroll
            for (int nfl = 0; nfl < 4; nfl++) {
                int rB = nfl * 16 + ln;
                bf16x8 b = *(const bf16x8*)((const char*)wt + rB * 256 + (cbyte ^ ((rB & 7) << 4)));
                acc2[s * 4 + nfl] =
                    __builtin_amdgcn_mfma_f32_16x16x32_bf16(a, b, acc2[s * 4 + nfl], 0, 0, 0);
            }
        }
        if (s == 0) {
            __syncthreads();
#pragma unroll
            for (int i = 0; i < 4; i++) {
                int cbyte = (i * 256 + t) * 16;
                gload_lds16((const char*)cwn + 16384 + cbyte, (char*)wt + cbyte);
            }
            __syncthreads();
        }
    }
#pragma unroll
    for (int nf = 0; nf < 8; nf++) {
        int col = nf * 16 + ln;
#pragma unroll
        for (int r4 = 0; r4 < 4; r4++) {
            int row2 = r0 + w * 16 + quad * 4 + r4;
            if (row2 < NN) zout[(long long)row2 * GCH + col] = f2bf(acc2[nf][r4]);
        }
    }
}

// ---- k_last: agg(7) + final LN(256) -> LDS + gemm(W2 from global) -> out.
//      32KB LDS -> 5 blocks/CU.
__global__ __launch_bounds__(256, 5) void k_last(
    const int* __restrict__ rowptr, const unsigned int* __restrict__ epk,
    const unsigned short* __restrict__ zin,
    const float* __restrict__ cb,
    unsigned short* __restrict__ h,
    const float* __restrict__ fgf, const float* __restrict__ fbf,
    const unsigned short* __restrict__ w2t,   // pre-swizzled [48][256]
    const float* __restrict__ b2f,
    const int* __restrict__ flags,
    void* __restrict__ out)
{
    __shared__ __align__(16) unsigned short a_tile[64 * 256];   // 32KB
    int t = threadIdx.x;
    int r0 = blockIdx.x * 64;
    int c8 = (t & 15) << 3;
    const int out_half = 1;

#pragma unroll 1
    for (int bt = 0; bt < 4; bt++) {
        int row = bt * 16 + (t >> 4);
        int node = r0 + row;
        if (node < NN) {
            int beg = rowptr[node], end = rowptr[node + 1];
            unsigned short* hp = h + (long long)node * HIDC + out_half * GCH + c8;
            u16x8 hv = *(u16x8*)hp;
            const unsigned short* zb = zin + c8;
            float acc[8];
#pragma unroll
            for (int j = 0; j < 8; j++) acc[j] = 0.f;

            int e = beg;
            for (; e + 7 < end; e += 8) {
                unsigned int pe[8];
                u16x8 v[8];
#pragma unroll
                for (int i = 0; i < 8; i++) pe[i] = epk[e + i];
#pragma unroll
                for (int i = 0; i < 8; i++)
                    v[i] = *(const u16x8*)(zb + (long long)(pe[i] & 0xFFFFu) * GCH);
#pragma unroll
                for (int i = 0; i < 8; i++) {
                    float wv = bf2f((unsigned short)(pe[i] >> 16));
#pragma unroll
                    for (int j = 0; j < 8; j++) acc[j] += wv * bf2f(v[i][j]);
                }
            }
            if (e + 3 < end) {
                unsigned int pe[4];
                u16x8 v[4];
#pragma unroll
                for (int i = 0; i < 4; i++) pe[i] = epk[e + i];
#pragma unroll
                for (int i = 0; i < 4; i++)
                    v[i] = *(const u16x8*)(zb + (long long)(pe[i] & 0xFFFFu) * GCH);
#pragma unroll
                for (int i = 0; i < 4; i++) {
                    float wv = bf2f((unsigned short)(pe[i] >> 16));
#pragma unroll
                    for (int j = 0; j < 8; j++) acc[j] += wv * bf2f(v[i][j]);
                }
                e += 4;
            }
            for (; e < end; e++) {
                unsigned int pe = epk[e];
                float w0 = bf2f((unsigned short)(pe >> 16));
                u16x8 v = *(const u16x8*)(zb + (long long)(pe & 0xFFFFu) * GCH);
#pragma unroll
                for (int j = 0; j < 8; j++) acc[j] += w0 * bf2f(v[j]);
            }

            float y[8]; float sum = 0.f, sq = 0.f;
#pragma unroll
            for (int j = 0; j < 8; j++) {
                float yy = bf2f(hv[j]) + acc[j] + cb[c8 + j];
                unsigned short r = f2bf(yy);
                hv[j] = r;
                y[j] = bf2f(r);
                sum += y[j]; sq += y[j] * y[j];
            }
            *(u16x8*)hp = hv;

            float oy[8];
            u16x8 ov = *(const u16x8*)(h + (long long)node * HIDC + (out_half ^ 1) * GCH + c8);
#pragma unroll
            for (int j = 0; j < 8; j++) {
                oy[j] = bf2f(ov[j]);
                sum += oy[j]; sq += oy[j] * oy[j];
            }
            sum += __shfl_xor(sum, 1, 64); sum += __shfl_xor(sum, 2, 64);
            sum += __shfl_xor(sum, 4, 64); sum += __shfl_xor(sum, 8, 64);
            sq  += __shfl_xor(sq, 1, 64);  sq  += __shfl_xor(sq, 2, 64);
            sq  += __shfl_xor(sq, 4, 64);  sq  += __shfl_xor(sq, 8, 64);
            float mu = sum * (1.0f / HIDC);
            float var = sq * (1.0f / HIDC) - mu * mu;
            float rs = rsqrtf(var + EPSV);

            u16x8 o;
            int cn = out_half * GCH + c8;
#pragma unroll
            for (int j = 0; j < 8; j++) {
                float val = (y[j] - mu) * rs * fgf[cn + j] + fbf[cn + j];
                if (val < 0.f) val = 0.f;
                o[j] = f2bf(val);
            }
            *(u16x8*)((char*)a_tile + row * 512 + ((cn * 2) ^ ((row & 7) << 4))) = o;
            int co = (out_half ^ 1) * GCH + c8;
#pragma unroll
            for (int j = 0; j < 8; j++) {
                float val = (oy[j] - mu) * rs * fgf[co + j] + fbf[co + j];
                if (val < 0.f) val = 0.f;
                o[j] = f2bf(val);
            }
            *(u16x8*)((char*)a_tile + row * 512 + ((co * 2) ^ ((row & 7) << 4))) = o;
        }
    }
    __syncthreads();

    int w = t >> 6, lane = t & 63, quad = lane >> 4, ln = lane & 15;
    const f32x4 zf = {0.f, 0.f, 0.f, 0.f};
    f32x4 acc2[3];
#pragma unroll
    for (int j = 0; j < 3; j++) acc2[j] = zf;
#pragma unroll
    for (int kk = 0; kk < 8; kk++) {
        int cbyte = kk * 64 + quad * 16;
        int ko = kk * 32 + quad * 8;
        int row = w * 16 + ln;
        bf16x8 a = *(const bf16x8*)((const char*)a_tile + row * 512 + (cbyte ^ ((row & 7) << 4)));
#pragma unroll
        for (int nf = 0; nf < 3; nf++) {
            int rB = nf * 16 + ln;
            // W2 fragment direct from global (L2-hot, swizzled layout)
            bf16x8 b = ld8(w2t + rB * 256 + (ko ^ ((rB & 7) << 3)));
            acc2[nf] = __builtin_amdgcn_mfma_f32_16x16x32_bf16(a, b, acc2[nf], 0, 0, 0);
        }
    }
    int f32o = flags[1];
#pragma unroll
    for (int nf = 0; nf < 3; nf++) {
        int col = nf * 16 + ln;
        if (col >= OUTC) continue;
        float bias = b2f[col];
#pragma unroll
        for (int r4 = 0; r4 < 4; r4++) {
            int row2 = r0 + w * 16 + quad * 4 + r4;
            if (row2 < NN) {
                float val = acc2[nf][r4] + bias;
                long long o = (long long)row2 * OUTC + col;
                if (f32o) ((float*)out)[o] = val;
                else      ((unsigned short*)out)[o] = f2bf(val);
            }
        }
    }
}

extern "C" void kernel_launch(void* const* d_in, const int* in_sizes, int n_in,
                              void* d_out, int out_size, void* d_ws, size_t ws_size,
                              hipStream_t stream)
{
    const void* x       = d_in[0];
    const int*  ei      = (const int*)d_in[1];
    const void* ew      = d_in[2];
    const void* lin1_w  = d_in[3];
    const void* lin1_b  = d_in[4];
    const void* lin2_w  = d_in[5];
    const void* lin2_b  = d_in[6];
    const void* norm_g  = d_in[7];
    const void* norm_b  = d_in[8];
    const void* conv_w  = d_in[9];
    const void* conv_b  = d_in[10];
    const void* fnorm_g = d_in[11];
    const void* fnorm_b = d_in[12];

    char* ws = (char*)d_ws;
    size_t off = 0;
    auto alloc = [&](size_t bytes) { void* p = (void*)(ws + off); off += (bytes + 255) & ~255ull; return p; };

    unsigned short* h      = (unsigned short*)alloc((size_t)NN * HIDC * 2);
    unsigned short* z0     = (unsigned short*)alloc((size_t)NN * GCH * 2);
    unsigned short* z1     = (unsigned short*)alloc((size_t)NN * GCH * 2);
    unsigned short* w1t    = (unsigned short*)alloc((size_t)CVT_W1 * 2);
    unsigned short* cwt    = (unsigned short*)alloc((size_t)CVT_CW * 2);
    unsigned short* w2t    = (unsigned short*)alloc((size_t)CVT_W2 * 2);
    float*          b1f    = (float*)alloc(256 * 4);
    float*          ngf    = (float*)alloc(1024 * 4);
    float*          nbf    = (float*)alloc(1024 * 4);
    float*          cbf    = (float*)alloc(1024 * 4);
    float*          fgf    = (float*)alloc(256 * 4);
    float*          fbf    = (float*)alloc(256 * 4);
    float*          b2f    = (float*)alloc(48 * 4);
    int*            deg    = (int*)alloc((size_t)NN * 4);
    int*            rowptr = (int*)alloc(((size_t)NN + 1) * 4);
    int*            cursor = (int*)alloc((size_t)NN * 4);
    unsigned int*   epk    = (unsigned int*)alloc((size_t)NEDGE * 4);
    int*            flags  = (int*)alloc(256);
    int*            bsum   = (int*)alloc(SCAN_B * 4);

    if (ws_size < off || n_in < 13) {
        float mv = 100.0f + (float)(ws_size >> 20) + ((n_in < 13) ? 10000.0f : 0.0f);
        k_marker<<<(out_size + 255) / 256, 256, 0, stream>>>(d_out, mv, out_size);
        return;
    }

    k_detect<<<196, 256, 0, stream>>>(ei, (const unsigned short*)x, flags, deg);
    k_convert<<<CVT_TOT / 256 + 1, 256, 0, stream>>>(lin1_w, conv_w, lin2_w,
                                                     lin1_b, norm_g, norm_b, conv_b,
                                                     fnorm_g, fnorm_b, lin2_b, flags,
                                                     w1t, cwt, w2t,
                                                     b1f, ngf, nbf, cbf, fgf, fbf, b2f);
    k_count<<<(NEDGE / 2 + 255) / 256, 256, 0, stream>>>(ei, flags, deg);
    k_scan_a<<<SCAN_B, 256, 0, stream>>>(deg, bsum);
    k_scan_c<<<SCAN_B, 256, 0, stream>>>(deg, bsum, rowptr, cursor);
    k_fill<<<(NEDGE / 2 + 255) / 256, 256, 0, stream>>>(ei, ew, flags, cursor, epk);

    const int GB = (NN + 63) / 64;   // 782
    k_first<<<GB, 256, 0, stream>>>(x, w1t, b1f, ngf, nbf, cwt, flags, h, z0);
    for (int lg = 0; lg < NL * NG - 1; lg++) {
        unsigned short* zin  = (lg & 1) ? z1 : z0;
        unsigned short* zout = (lg & 1) ? z0 : z1;
        k_fused<<<GB, 256, 0, stream>>>(rowptr, epk, zin, cbf + lg * GCH, h, lg & 1,
                                        ngf + (lg + 1) * GCH, nbf + (lg + 1) * GCH,
                                        cwt + (size_t)(lg + 1) * 16384, zout);
    }
    k_last<<<GB, 256, 0, stream>>>(rowptr, epk, z1, cbf + 7 * GCH, h,
                                   fgf, fbf, w2t, b2f, flags, d_out);
}